// Round 14
// baseline (246.948 us; speedup 1.0000x reference)
//
#include <hip/hip_runtime.h>
#include <math.h>

// Problem constants (B=1, LAYERS=33, HEADS=20, SEQ=512)
#define SEQ   512
#define NF    660
#define CROP  510
#define EOSI  2
#define RT    32           // rows per block (pass1)  [R14: 16 -> 32]
#define GH    20           // heads per group (pass1)
#define NT_   16           // row tiles               [R14: 32 -> 16]
#define NG    33           // head groups

typedef float    f4 __attribute__((ext_vector_type(4)));
typedef _Float16 h4 __attribute__((ext_vector_type(4)));

// load one batch (4 rows x wave's 128-col strip): two f4 per lane
#define LOADB(d0, d1, ptr) do {                                               \
    d0 = *(const f4*)(ptr);                                                   \
    d1 = *(const f4*)((ptr) + 64);                                            \
} while (0)

// consume one batch b (4 rows): WA acc, masked row-sum partial (butterfly
// over c8), masked col-sum acc. NO barrier, NO global store.
#define CONS(x0, x1, b, h) do {                                               \
    float vals[8] = {x0[0], x0[1], x0[2], x0[3],                              \
                     x1[0], x1[1], x1[2], x1[3]};                             \
    float rs = 0.f;                                                           \
    const float mb = mrow[b];                                                 \
    _Pragma("unroll")                                                         \
    for (int e = 0; e < 8; ++e) {                                             \
        const float v = vals[e];                                              \
        wa_acc[b][e] += wf * v;                                               \
        rs += mskv[e] * v;                                                    \
        cacc[e] += mb * v;                                                    \
    }                                                                         \
    rs += __shfl_xor(rs, 1, 64);                                              \
    rs += __shfl_xor(rs, 2, 64);                                              \
    rs += __shfl_xor(rs, 4, 64);                                              \
    rs += __shfl_xor(rs, 8, 64);                                              \
    if (c8 == 0) rowpart[h][(b) * 4 + r][wave] = rs;                          \
} while (0)

// ---------------- Pass 1: stream 692MB, barrier-free (R11 structure) --------
// grid (16 row-tiles, 33 head-groups), block 256 (4 waves), all-resident.
// Wave w owns cols [128w,128w+128) for all 32 rows; 8 batches of 4 rows per
// head. Col-sum has NO cross-wave combine; hot loop: zero barriers, zero
// global stores. colpart stays f32 (feeds a1/a12 -- fp16 there amplifies via
// 1/a12, R13 failure). WApart is fp16 (linear WA term only -- safe).
__global__ __launch_bounds__(256) void pass1_kernel(
    const float* __restrict__ A, const int* __restrict__ tokens,
    const float* __restrict__ weight,
    _Float16* __restrict__ WApart, float* __restrict__ rowsum,
    float* __restrict__ colpart)
{
    __shared__ float msk[SEQ];                // 2 KB
    __shared__ float colstage[GH][SEQ];       // 40 KB, wave-exclusive 128-col strips
    __shared__ float rowpart[GH][RT][4];      // 10 KB per-wave row partials

    const int t = blockIdx.x, g = blockIdx.y;
    const int tid = threadIdx.x, wave = tid >> 6, lane = tid & 63;
    const int r = lane >> 4, c8 = lane & 15;
    const int fbase = g * GH;
    const int row0 = t * RT;
    const int col0 = wave * 128;

    for (int j = tid; j < SEQ; j += 256)
        msk[j] = (j >= 1 && j <= SEQ - 2 && tokens[j] != EOSI) ? 1.f : 0.f;
    __syncthreads();

    float mskv[8];
    #pragma unroll
    for (int p = 0; p < 2; ++p)
        #pragma unroll
        for (int k = 0; k < 4; ++k)
            mskv[p * 4 + k] = msk[col0 + p * 64 + c8 * 4 + k];
    float mrow[8];
    #pragma unroll
    for (int b = 0; b < 8; ++b) mrow[b] = msk[row0 + b * 4 + r];

    float wa_acc[8][8];
    #pragma unroll
    for (int b = 0; b < 8; ++b)
        #pragma unroll
        for (int e = 0; e < 8; ++e) wa_acc[b][e] = 0.f;

    // per-lane offset within a head: (row0 + r)*512 + col0 + c8*4
    const size_t lofs = (size_t)(row0 + r) * SEQ + col0 + c8 * 4;

    f4 a0, a1, b0, b1;
    {   // prime: head 0, batch 0
        const float* Ah = A + ((size_t)fbase << 18) + lofs;
        LOADB(a0, a1, Ah);
    }

    #pragma unroll 1
    for (int h = 0; h < GH; ++h) {
        const float wf = weight[fbase + h];
        const float* __restrict__ Ah = A + ((size_t)(fbase + h) << 18) + lofs;
        float cacc[8] = {0, 0, 0, 0, 0, 0, 0, 0};

        LOADB(b0, b1, Ah + 2048);              CONS(a0, a1, 0, h);
        LOADB(a0, a1, Ah + 4096);              CONS(b0, b1, 1, h);
        LOADB(b0, b1, Ah + 6144);              CONS(a0, a1, 2, h);
        LOADB(a0, a1, Ah + 8192);              CONS(b0, b1, 3, h);
        LOADB(b0, b1, Ah + 10240);             CONS(a0, a1, 4, h);
        LOADB(a0, a1, Ah + 12288);             CONS(b0, b1, 5, h);
        LOADB(b0, b1, Ah + 14336);             CONS(a0, a1, 6, h);
        if (h < GH - 1) LOADB(a0, a1, Ah + 262144);   // next head, batch 0
        CONS(b0, b1, 7, h);

        // col-sum: butterfly across the 4 r-groups (within wave), then write
        // this wave's exclusive 128-col strip of colstage[h] (LDS, f32)
        #pragma unroll
        for (int e = 0; e < 8; ++e) {
            cacc[e] += __shfl_xor(cacc[e], 16, 64);
            cacc[e] += __shfl_xor(cacc[e], 32, 64);
        }
        if (r == 0) {
            f4 s = {cacc[0], cacc[1], cacc[2], cacc[3]};
            *(f4*)&colstage[h][col0 + c8 * 4] = s;
        } else if (r == 1) {
            f4 s = {cacc[4], cacc[5], cacc[6], cacc[7]};
            *(f4*)&colstage[h][col0 + 64 + c8 * 4] = s;
        }
    }

    __syncthreads();   // all waves' colstage strips + rowpart complete

    // ---- flush colstage -> colpart (f32): 20 heads x 512 cols contiguous
    {
        float* __restrict__ dst = colpart + ((size_t)t * NF + fbase) * SEQ;
        const float* __restrict__ src = &colstage[0][0];
        #pragma unroll
        for (int it = 0; it < 10; ++it) {
            const int fl = (it * 256 + tid) * 4;
            *(f4*)(dst + fl) = *(const f4*)(src + fl);
        }
    }
    // ---- reduce rowpart (4 wave-strips) -> rowsum; 20*32=640 > 256: 3 iters
    #pragma unroll
    for (int it = 0; it < 3; ++it) {
        const int e = it * 256 + tid;
        if (e < GH * RT) {
            const int h = e >> 5, i = e & 31;
            rowsum[((size_t)(fbase + h) << 9) + row0 + i] =
                rowpart[h][i][0] + rowpart[h][i][1] + rowpart[h][i][2] + rowpart[h][i][3];
        }
    }
    // ---- flush WApart (fp16, write-once; wave-exclusive col strips)
    {
        _Float16* __restrict__ wp = WApart + (size_t)g * SEQ * SEQ + lofs;
        #pragma unroll
        for (int b = 0; b < 8; ++b) {
            h4 o0 = {(_Float16)wa_acc[b][0], (_Float16)wa_acc[b][1],
                     (_Float16)wa_acc[b][2], (_Float16)wa_acc[b][3]};
            h4 o1 = {(_Float16)wa_acc[b][4], (_Float16)wa_acc[b][5],
                     (_Float16)wa_acc[b][6], (_Float16)wa_acc[b][7]};
            _Float16* dst = wp + (size_t)b * 4 * SEQ;
            *(h4*)dst = o0;
            *(h4*)(dst + 64) = o1;
        }
    }
}

// ---------------- Kernel 2 (merged): WA-reduce + per-head a1/a12/scale --------
// Blocks [0,128): WA(f32) = sum_g WApart_fp16[g]. Blocks [128,788): a1/a12/sfac
// from f32 rowsum/colpart (exact path -- no reduced precision here).
__global__ __launch_bounds__(512) void kernel2(
    const _Float16* __restrict__ WApart, float* __restrict__ WA,
    const float* __restrict__ rowsum, const float* __restrict__ colpart,
    const int* __restrict__ tokens, const float* __restrict__ weight,
    float* __restrict__ a1, float* __restrict__ sfac)
{
    __shared__ float part[8];
    const int b = blockIdx.x, tid = threadIdx.x;
    if (b < 128) {
        const size_t idx4 = (size_t)b * 512 + tid;     // 4-elem chunk, 65536 total
        const h4* __restrict__ src = (const h4*)WApart;
        h4 x = src[idx4];
        f4 a = {(float)x[0], (float)x[1], (float)x[2], (float)x[3]};
        #pragma unroll 8
        for (int g = 1; g < NG; ++g) {
            h4 y = src[(size_t)g * (SEQ * SEQ / 4) + idx4];
            a[0] += (float)y[0]; a[1] += (float)y[1];
            a[2] += (float)y[2]; a[3] += (float)y[3];
        }
        *(f4*)(WA + 4 * idx4) = a;
    } else {
        const int f = b - 128, j = tid;
        float cs = 0.f;
        #pragma unroll 8
        for (int t = 0; t < NT_; ++t)
            cs += colpart[((size_t)t * NF + f) * SEQ + j];
        const float m = (j >= 1 && j <= SEQ - 2 && tokens[j] != EOSI) ? 1.f : 0.f;
        const float v = m * (rowsum[((size_t)f << 9) + j] + cs);
        a1[((size_t)f << 9) + j] = v;
        float s = v;
        #pragma unroll
        for (int off = 32; off > 0; off >>= 1)
            s += __shfl_down(s, off, 64);
        const int wave = tid >> 6, lane = tid & 63;
        if (lane == 0) part[wave] = s;
        __syncthreads();
        if (tid == 0) {
            float a12 = 0.f;
            #pragma unroll
            for (int k = 0; k < 8; ++k) a12 += part[k];
            sfac[f] = weight[f] / a12;
        }
    }
}

// ---------------- Pass 3: rank-660 outer-product + WA + sigmoid ----------------
// grid (32,32) = 1024 blocks; 16x16 output tile, 1 output/thread; 32-f chunks
__global__ __launch_bounds__(256) void pass3_kernel(
    const float* __restrict__ WA, const float* __restrict__ a1,
    const float* __restrict__ sfac, const int* __restrict__ tokens,
    const float* __restrict__ bias, float* __restrict__ out)
{
    const int TI = blockIdx.y * 16;
    const int TJ = blockIdx.x * 16;
    const int tid = threadIdx.x;
    const int tx = tid & 15, ty = tid >> 4;

    __shared__ float u_s[32][17];
    __shared__ float v_s[32][17];

    float acc = 0.f;

    for (int f0 = 0; f0 < NF; f0 += 32) {
        #pragma unroll
        for (int c = 0; c < 4; ++c) {
            const int e = c * 256 + tid;        // 0..1023
            const int arr = e >> 9, ff = (e >> 4) & 31, ii = e & 15;
            const int f = f0 + ff;
            float val = 0.f;
            if (f < NF) {
                if (arr == 0) {
                    int Iu = TI + 1 + ii; if (Iu > SEQ - 1) Iu = SEQ - 1;
                    val = a1[((size_t)f << 9) + Iu] * sfac[f];
                } else {
                    int Ju = TJ + 1 + ii; if (Ju > SEQ - 1) Ju = SEQ - 1;
                    val = a1[((size_t)f << 9) + Ju];
                }
            }
            if (arr == 0) u_s[ff][ii] = val; else v_s[ff][ii] = val;
        }
        __syncthreads();
        #pragma unroll
        for (int ff = 0; ff < 32; ++ff)
            acc += u_s[ff][ty] * v_s[ff][tx];
        __syncthreads();
    }

    const int i = TI + ty, j = TJ + tx;
    if (i < CROP && j < CROP) {
        const int I = i + 1, J = j + 1;
        const float mi = (tokens[I] != EOSI) ? 1.f : 0.f;
        const float mj = (tokens[J] != EOSI) ? 1.f : 0.f;
        const float first = mi * mj * (WA[((size_t)I << 9) + J] + WA[((size_t)J << 9) + I]);
        const float logit = first - acc + bias[0];
        out[(size_t)i * CROP + j] = 1.f / (1.f + expf(-logit));
    }
}

extern "C" void kernel_launch(void* const* d_in, const int* in_sizes, int n_in,
                              void* d_out, int out_size, void* d_ws, size_t ws_size,
                              hipStream_t stream) {
    const int*   tokens = (const int*)d_in[0];
    const float* A      = (const float*)d_in[1];
    const float* weight = (const float*)d_in[2];
    const float* bias   = (const float*)d_in[3];
    float* out = (float*)d_out;

    // workspace layout (all write-once, no zeroing):
    //   fp16: WApart[33*512*512]
    //   f32:  colpart[16*660*512] | WA[512*512] | rowsum[660*512] | a1[660*512] | sfac[660]
    _Float16* WApart  = (_Float16*)d_ws;
    float* colpart = (float*)(WApart + (size_t)NG * SEQ * SEQ);
    float* WA      = colpart + (size_t)NT_ * NF * SEQ;
    float* rowsum  = WA + (size_t)SEQ * SEQ;
    float* a1      = rowsum + (size_t)NF * SEQ;
    float* sfac    = a1 + (size_t)NF * SEQ;

    dim3 g1(NT_, NG);   // 16 x 33 = 528 blocks (all resident at 3 blocks/CU)
    pass1_kernel<<<g1, 256, 0, stream>>>(A, tokens, weight, WApart, rowsum, colpart);

    kernel2<<<128 + NF, 512, 0, stream>>>(WApart, WA, rowsum, colpart, tokens, weight, a1, sfac);

    dim3 g3(32, 32);
    pass3_kernel<<<g3, 256, 0, stream>>>(WA, a1, sfac, tokens, bias, out);
}

// Round 15
// 215.182 us; speedup vs baseline: 1.1476x; 1.1476x over previous
//
#include <hip/hip_runtime.h>
#include <math.h>

// Problem constants (B=1, LAYERS=33, HEADS=20, SEQ=512)
#define SEQ   512
#define NF    660
#define CROP  510
#define EOSI  2
#define RT    16           // rows per block (pass1)
#define GH    20           // heads per group (pass1)
#define NT_   32           // row tiles
#define NG    33           // head groups

typedef float f4 __attribute__((ext_vector_type(4)));

// load one batch (4 rows x wave's 128-col strip): two f4 per lane
#define LOADB(d0, d1, ptr) do {                                               \
    d0 = *(const f4*)(ptr);                                                   \
    d1 = *(const f4*)((ptr) + 64);                                            \
} while (0)

// consume one batch b: WA acc, masked row-sum partial (butterfly over c8),
// masked col-sum acc. NO barrier, NO global store.
#define CONS(x0, x1, b, h) do {                                               \
    float vals[8] = {x0[0], x0[1], x0[2], x0[3],                              \
                     x1[0], x1[1], x1[2], x1[3]};                             \
    float rs = 0.f;                                                           \
    const float mb = mrow[b];                                                 \
    _Pragma("unroll")                                                         \
    for (int e = 0; e < 8; ++e) {                                             \
        const float v = vals[e];                                              \
        wa_acc[b][e] += wf * v;                                               \
        rs += mskv[e] * v;                                                    \
        cacc[e] += mb * v;                                                    \
    }                                                                         \
    rs += __shfl_xor(rs, 1, 64);                                              \
    rs += __shfl_xor(rs, 2, 64);                                              \
    rs += __shfl_xor(rs, 4, 64);                                              \
    rs += __shfl_xor(rs, 8, 64);                                              \
    if (c8 == 0) rowpart[h][(b) * 4 + r][wave] = rs;                          \
} while (0)

// ---------------- Pass 1: stream 692MB, barrier-free hot loop ----------------
// grid (32 row-tiles, 33 head-groups), block 256 (4 waves).
// Wave w owns cols [128w,128w+128) for all 16 rows -> col-sum needs NO
// cross-wave combine; row-sum partials go to a 5KB LDS array reduced at end.
// Hot loop: zero barriers, zero global stores, waves fully independent.
// LDS 47KB -> 3 blocks/CU = 12 waves/CU; lean VGPR (~100), no bounds gamble.
__global__ __launch_bounds__(256) void pass1_kernel(
    const float* __restrict__ A, const int* __restrict__ tokens,
    const float* __restrict__ weight,
    float* __restrict__ WApart, float* __restrict__ rowsum, float* __restrict__ colpart)
{
    __shared__ float msk[SEQ];                // 2 KB
    __shared__ float colstage[GH][SEQ];       // 40 KB, wave-exclusive 128-col strips
    __shared__ float rowpart[GH][RT][4];      // 5 KB per-wave row partials

    const int t = blockIdx.x, g = blockIdx.y;
    const int tid = threadIdx.x, wave = tid >> 6, lane = tid & 63;
    const int r = lane >> 4, c8 = lane & 15;
    const int fbase = g * GH;
    const int row0 = t * RT;
    const int col0 = wave * 128;

    for (int j = tid; j < SEQ; j += 256)
        msk[j] = (j >= 1 && j <= SEQ - 2 && tokens[j] != EOSI) ? 1.f : 0.f;
    __syncthreads();

    float mskv[8];
    #pragma unroll
    for (int p = 0; p < 2; ++p)
        #pragma unroll
        for (int k = 0; k < 4; ++k)
            mskv[p * 4 + k] = msk[col0 + p * 64 + c8 * 4 + k];
    float mrow[4];
    #pragma unroll
    for (int b = 0; b < 4; ++b) mrow[b] = msk[row0 + b * 4 + r];

    float wa_acc[4][8];
    #pragma unroll
    for (int b = 0; b < 4; ++b)
        #pragma unroll
        for (int e = 0; e < 8; ++e) wa_acc[b][e] = 0.f;

    // per-lane offset within a head: (row0 + r)*512 + col0 + c8*4
    const size_t lofs = (size_t)(row0 + r) * SEQ + col0 + c8 * 4;

    f4 a0, a1, b0, b1;
    {   // prime: head 0, batch 0
        const float* Ah = A + ((size_t)fbase << 18) + lofs;
        LOADB(a0, a1, Ah);
    }

    #pragma unroll 1
    for (int h = 0; h < GH; ++h) {
        const float wf = weight[fbase + h];
        const float* __restrict__ Ah = A + ((size_t)(fbase + h) << 18) + lofs;
        float cacc[8] = {0, 0, 0, 0, 0, 0, 0, 0};

        LOADB(b0, b1, Ah + 2048);             // batch 1
        CONS(a0, a1, 0, h);
        LOADB(a0, a1, Ah + 4096);             // batch 2
        CONS(b0, b1, 1, h);
        LOADB(b0, b1, Ah + 6144);             // batch 3
        CONS(a0, a1, 2, h);
        if (h < GH - 1) LOADB(a0, a1, Ah + 262144);   // next head, batch 0
        CONS(b0, b1, 3, h);

        // col-sum: butterfly across the 4 r-groups (within wave), then write
        // this wave's exclusive 128-col strip of colstage[h]
        #pragma unroll
        for (int e = 0; e < 8; ++e) {
            cacc[e] += __shfl_xor(cacc[e], 16, 64);
            cacc[e] += __shfl_xor(cacc[e], 32, 64);
        }
        if (r == 0) {
            f4 s = {cacc[0], cacc[1], cacc[2], cacc[3]};
            *(f4*)&colstage[h][col0 + c8 * 4] = s;
        } else if (r == 1) {
            f4 s = {cacc[4], cacc[5], cacc[6], cacc[7]};
            *(f4*)&colstage[h][col0 + 64 + c8 * 4] = s;
        }
    }

    __syncthreads();   // all waves' colstage strips + rowpart complete

    // ---- flush colstage -> colpart: 20 heads x 512 cols contiguous (40 KB)
    {
        float* __restrict__ dst = colpart + ((size_t)t * NF + fbase) * SEQ;
        const float* __restrict__ src = &colstage[0][0];
        #pragma unroll
        for (int it = 0; it < 10; ++it) {
            const int fl = (it * 256 + tid) * 4;
            *(f4*)(dst + fl) = *(const f4*)(src + fl);
        }
    }
    // ---- reduce rowpart (4 wave-strips) -> rowsum; GH*RT=320 > 256: loop!
    #pragma unroll
    for (int it = 0; it < 2; ++it) {
        const int e = it * 256 + tid;
        if (e < GH * RT) {
            const int h = e >> 4, i = e & 15;
            rowsum[((size_t)(fbase + h) << 9) + row0 + i] =
                rowpart[h][i][0] + rowpart[h][i][1] + rowpart[h][i][2] + rowpart[h][i][3];
        }
    }
    // ---- flush WApart (write-once, f4 coalesced; wave-exclusive col strips)
    {
        float* __restrict__ wp = WApart + (size_t)g * SEQ * SEQ + lofs;
        #pragma unroll
        for (int b = 0; b < 4; ++b) {
            f4 o0 = {wa_acc[b][0], wa_acc[b][1], wa_acc[b][2], wa_acc[b][3]};
            f4 o1 = {wa_acc[b][4], wa_acc[b][5], wa_acc[b][6], wa_acc[b][7]};
            float* dst = wp + (size_t)b * 4 * SEQ;
            *(f4*)dst = o0;
            *(f4*)(dst + 64) = o1;
        }
    }
}

// ---------------- Kernel 2 (merged): WA-reduce + per-head a1/a12/scale --------
__global__ __launch_bounds__(512) void kernel2(
    const float* __restrict__ WApart, float* __restrict__ WA,
    const float* __restrict__ rowsum, const float* __restrict__ colpart,
    const int* __restrict__ tokens, const float* __restrict__ weight,
    float* __restrict__ a1, float* __restrict__ sfac)
{
    __shared__ float part[8];
    const int b = blockIdx.x, tid = threadIdx.x;
    if (b < 128) {
        const size_t idx4 = (size_t)b * 512 + tid;     // float4 index, 65536 total
        f4 a = *(const f4*)(WApart + 4 * idx4);
        #pragma unroll 8
        for (int g = 1; g < NG; ++g) {
            f4 x = *(const f4*)(WApart + (size_t)g * (SEQ * SEQ) + 4 * idx4);
            a += x;
        }
        *(f4*)(WA + 4 * idx4) = a;
    } else {
        const int f = b - 128, j = tid;
        float cs = 0.f;
        #pragma unroll 8
        for (int t = 0; t < NT_; ++t)
            cs += colpart[((size_t)t * NF + f) * SEQ + j];
        const float m = (j >= 1 && j <= SEQ - 2 && tokens[j] != EOSI) ? 1.f : 0.f;
        const float v = m * (rowsum[((size_t)f << 9) + j] + cs);
        a1[((size_t)f << 9) + j] = v;
        float s = v;
        #pragma unroll
        for (int off = 32; off > 0; off >>= 1)
            s += __shfl_down(s, off, 64);
        const int wave = tid >> 6, lane = tid & 63;
        if (lane == 0) part[wave] = s;
        __syncthreads();
        if (tid == 0) {
            float a12 = 0.f;
            #pragma unroll
            for (int k = 0; k < 8; ++k) a12 += part[k];
            sfac[f] = weight[f] / a12;
        }
    }
}

// ---------------- Pass 3: rank-660 outer-product + WA + sigmoid ----------------
// grid (32,32) = 1024 blocks; 16x16 output tile, 1 output/thread; 32-f chunks
__global__ __launch_bounds__(256) void pass3_kernel(
    const float* __restrict__ WA, const float* __restrict__ a1,
    const float* __restrict__ sfac, const int* __restrict__ tokens,
    const float* __restrict__ bias, float* __restrict__ out)
{
    const int TI = blockIdx.y * 16;
    const int TJ = blockIdx.x * 16;
    const int tid = threadIdx.x;
    const int tx = tid & 15, ty = tid >> 4;

    __shared__ float u_s[32][17];
    __shared__ float v_s[32][17];

    float acc = 0.f;

    for (int f0 = 0; f0 < NF; f0 += 32) {
        #pragma unroll
        for (int c = 0; c < 4; ++c) {
            const int e = c * 256 + tid;        // 0..1023
            const int arr = e >> 9, ff = (e >> 4) & 31, ii = e & 15;
            const int f = f0 + ff;
            float val = 0.f;
            if (f < NF) {
                if (arr == 0) {
                    int Iu = TI + 1 + ii; if (Iu > SEQ - 1) Iu = SEQ - 1;
                    val = a1[((size_t)f << 9) + Iu] * sfac[f];
                } else {
                    int Ju = TJ + 1 + ii; if (Ju > SEQ - 1) Ju = SEQ - 1;
                    val = a1[((size_t)f << 9) + Ju];
                }
            }
            if (arr == 0) u_s[ff][ii] = val; else v_s[ff][ii] = val;
        }
        __syncthreads();
        #pragma unroll
        for (int ff = 0; ff < 32; ++ff)
            acc += u_s[ff][ty] * v_s[ff][tx];
        __syncthreads();
    }

    const int i = TI + ty, j = TJ + tx;
    if (i < CROP && j < CROP) {
        const int I = i + 1, J = j + 1;
        const float mi = (tokens[I] != EOSI) ? 1.f : 0.f;
        const float mj = (tokens[J] != EOSI) ? 1.f : 0.f;
        const float first = mi * mj * (WA[((size_t)I << 9) + J] + WA[((size_t)J << 9) + I]);
        const float logit = first - acc + bias[0];
        out[(size_t)i * CROP + j] = 1.f / (1.f + expf(-logit));
    }
}

extern "C" void kernel_launch(void* const* d_in, const int* in_sizes, int n_in,
                              void* d_out, int out_size, void* d_ws, size_t ws_size,
                              hipStream_t stream) {
    const int*   tokens = (const int*)d_in[0];
    const float* A      = (const float*)d_in[1];
    const float* weight = (const float*)d_in[2];
    const float* bias   = (const float*)d_in[3];
    float* out = (float*)d_out;

    // workspace (floats), all write-once, no zeroing:
    // WApart[33*512*512] | colpart[32*660*512] | WA[512*512] | rowsum[660*512] | a1[660*512] | sfac[660]
    float* WApart  = (float*)d_ws;
    float* colpart = WApart + (size_t)NG * SEQ * SEQ;
    float* WA      = colpart + (size_t)NT_ * NF * SEQ;
    float* rowsum  = WA + (size_t)SEQ * SEQ;
    float* a1      = rowsum + (size_t)NF * SEQ;
    float* sfac    = a1 + (size_t)NF * SEQ;

    dim3 g1(NT_, NG);   // 32 x 33
    pass1_kernel<<<g1, 256, 0, stream>>>(A, tokens, weight, WApart, rowsum, colpart);

    kernel2<<<128 + NF, 512, 0, stream>>>(WApart, WA, rowsum, colpart, tokens, weight, a1, sfac);

    dim3 g3(32, 32);
    pass3_kernel<<<g3, 256, 0, stream>>>(WA, a1, sfac, tokens, bias, out);
}